// Round 2
// 101.431 us; speedup vs baseline: 1.0080x; 1.0080x over previous
//
#include <hip/hip_runtime.h>

#define NN 500000
#define NSEG 1024
#define REGC 4     // register-buffered iterations: covers len <= 1024 (observed max ~600)

// ---------------------------------------------------------------------------
// Single fused kernel, one block (256 thr) per segment.
// Math: the psi-MLP -> segment-mean -> rho -> agg-part of keys is constant per
// segment+head, and the per-segment softmax is shift-invariant => it all
// cancels. pre[n,h] = x_n . Vx[:,h], Vx = Wk[0:16].Wq/sqrt(64). |pre| << 1 by
// construction (Vx std ~2.4e-3), so exp needs no max subtraction.
//
// This revision vs baseline (101-102 us end-to-end, attn slice ~14 us):
//  - 2-round guess-windowed lower_bound (segment starts deviate from the
//    uniform prior s*NN/NSEG by sigma<=354 binomial; +-4096 window = 11.5
//    sigma; full 64-ary search fallback keeps it correct for ANY sorted seg).
//    Cuts the dependent-gather startup chain from 4 rounds to 2.
//  - Branchless clamped loads in the fast path: all REGC*4 dwordx4 loads
//    issue unconditionally (inactive lanes re-load row len-1 -> L1 hit),
//    masked accumulate. Maximizes per-wave MLP.
//  - Single __syncthreads in the reduction: each thread folds the 4 per-wave
//    partials itself; v_rcp_f32 (rel err ~1e-7, irrelevant vs 2e-3 outputs).
//  - float4-vectorized Vx fold.
// (Resubmission of round-1 source: bench failure was an infra container
//  error; OOB/termination audit found no kernel-side hang mechanism.)
// ---------------------------------------------------------------------------
__launch_bounds__(256, 4)
__global__ void attn_kernel(const float* __restrict__ x,
                            const int* __restrict__ seg,
                            const float* __restrict__ Wk,
                            const float* __restrict__ Wq,
                            float* __restrict__ out) {
  __shared__ float sVx[64];       // [c][h] c<16 h<4
  __shared__ int   rng[2];
  __shared__ float4 red4[4];      // per-wave partial denominators

  int s = blockIdx.x, t = threadIdx.x;
  int wv = t >> 6, lane = t & 63;

  if (wv < 2) {
    int target = s + wv;
    int r = -1;
    // window centered on the uniform-prior guess
    long long gl = (long long)target * NN / NSEG;
    int W0 = (int)gl - 4096;
    if (W0 < 0) W0 = 0;
    if (W0 > NN - 8192) W0 = NN - 8192;
    // round 1: 64 probes, stride 128 (span 8192)
    int p = W0 + (lane << 7);                 // p <= W0+8064 <= NN-128
    bool lt = seg[p] < target;
    int c = __popcll(__ballot(lt));
    if (c == 0) {
      if (W0 == 0) r = 0;                     // else: boundary left of window -> fallback
    } else {
      int low = W0 + ((c - 1) << 7);          // seg[low] < target
      if (!(c == 64 && low + 128 < NN)) {     // c==64 inside array -> fallback
        // round 2: 128 contiguous probes via 2 loads/lane over (low, low+128]
        int q1 = low + 1 + lane;
        int q2 = q1 + 64;
        bool l1 = (q1 < NN) && (seg[q1] < target);
        bool l2 = (q2 < NN) && (seg[q2] < target);
        int c1 = __popcll(__ballot(l1));
        int c2 = __popcll(__ballot(l2));
        r = low + 1 + c1 + c2;
      }
    }
    if (r < 0) {
      // fallback: full 64-ary ballot search (correct for any sorted data)
      int lo = 0, hi = NN;
      while (true) {
        int width = hi - lo;
        if (width <= 0) { r = lo; break; }
        if (width <= 64) {
          int pos = lo + lane;
          bool flt = (pos < hi) && (seg[pos] < target);
          r = lo + __popcll(__ballot(flt));
          break;
        }
        int step = (width + 63) >> 6;
        int pos = lo + lane * step;
        bool flt = (pos < hi) && (seg[pos] < target);
        int cc = __popcll(__ballot(flt));
        if (cc == 0) { r = lo; break; }
        hi = min(lo + cc * step, hi);
        lo = lo + (cc - 1) * step + 1;
      }
    }
    if (lane == 0) rng[wv] = r;
  } else if (wv == 2) {
    // folded key-query weights (x part only), pre-scaled by 1/sqrt(DOT)
    int c = lane >> 2, h = lane & 3;
    const float4* wk4 = (const float4*)(Wk + c * 256 + h * 64);
    const float4* wq4 = (const float4*)(Wq + h * 64);
    float a = 0.f;
#pragma unroll
    for (int d4 = 0; d4 < 16; ++d4) {
      float4 wa = wk4[d4], wb = wq4[d4];
      a = fmaf(wa.x, wb.x, a); a = fmaf(wa.y, wb.y, a);
      a = fmaf(wa.z, wb.z, a); a = fmaf(wa.w, wb.w, a);
    }
    sVx[lane] = a * 0.125f;
  }
  __syncthreads();

  int lo = rng[0], hi = rng[1], len = hi - lo;
  if (len <= 0) return;   // empty segment: no elements to write (uniform exit)
  const float4* sVx4 = (const float4*)sVx;

  if (len <= REGC * 256) {
    // ---- fast path: e-values live in registers, branchless loads
    float4 e[REGC];
    float s0 = 0.f, s1 = 0.f, s2 = 0.f, s3 = 0.f;
#pragma unroll
    for (int it = 0; it < REGC; ++it) {
      int i = t + it * 256;
      int ic = (i < len) ? i : (len - 1);     // clamp: load always valid, L1-hit dup
      const float4* xp = (const float4*)(x + (size_t)(lo + ic) * 16);
      float4 a0 = xp[0], a1 = xp[1], a2 = xp[2], a3 = xp[3];
      float xv[16] = {a0.x,a0.y,a0.z,a0.w, a1.x,a1.y,a1.z,a1.w,
                      a2.x,a2.y,a2.z,a2.w, a3.x,a3.y,a3.z,a3.w};
      float p0 = 0.f, p1 = 0.f, p2 = 0.f, p3 = 0.f;
#pragma unroll
      for (int k = 0; k < 16; ++k) {
        float4 vh = sVx4[k];
        p0 = fmaf(xv[k], vh.x, p0);
        p1 = fmaf(xv[k], vh.y, p1);
        p2 = fmaf(xv[k], vh.z, p2);
        p3 = fmaf(xv[k], vh.w, p3);
      }
      float4 ev = { __expf(p0), __expf(p1), __expf(p2), __expf(p3) };
      e[it] = ev;
      float m = (i < len) ? 1.f : 0.f;        // mask inactive lanes out of the sum
      s0 = fmaf(ev.x, m, s0); s1 = fmaf(ev.y, m, s1);
      s2 = fmaf(ev.z, m, s2); s3 = fmaf(ev.w, m, s3);
    }
    for (int o = 1; o < 64; o <<= 1) {
      s0 += __shfl_xor(s0, o); s1 += __shfl_xor(s1, o);
      s2 += __shfl_xor(s2, o); s3 += __shfl_xor(s3, o);
    }
    if (lane == 0) red4[wv] = make_float4(s0, s1, s2, s3);
    __syncthreads();
    float4 ra = red4[0], rb = red4[1], rc = red4[2], rd = red4[3];
    float i0 = __builtin_amdgcn_rcpf(ra.x + rb.x + rc.x + rd.x);
    float i1 = __builtin_amdgcn_rcpf(ra.y + rb.y + rc.y + rd.y);
    float i2 = __builtin_amdgcn_rcpf(ra.z + rb.z + rc.z + rd.z);
    float i3 = __builtin_amdgcn_rcpf(ra.w + rb.w + rc.w + rd.w);
#pragma unroll
    for (int it = 0; it < REGC; ++it) {
      int i = t + it * 256;
      if (i < len) {
        float4 ev = e[it];
        ev.x *= i0; ev.y *= i1; ev.z *= i2; ev.w *= i3;
        *(float4*)(out + (size_t)(lo + i) * 4) = ev;
      }
    }
  } else {
    // ---- fallback (len > 1024, not expected): 2 passes via out as scratch
    float s0 = 0.f, s1 = 0.f, s2 = 0.f, s3 = 0.f;
    for (int i = t; i < len; i += 256) {
      const float4* xp = (const float4*)(x + (size_t)(lo + i) * 16);
      float4 a0 = xp[0], a1 = xp[1], a2 = xp[2], a3 = xp[3];
      float xv[16] = {a0.x,a0.y,a0.z,a0.w, a1.x,a1.y,a1.z,a1.w,
                      a2.x,a2.y,a2.z,a2.w, a3.x,a3.y,a3.z,a3.w};
      float p0 = 0.f, p1 = 0.f, p2 = 0.f, p3 = 0.f;
#pragma unroll
      for (int k = 0; k < 16; ++k) {
        float4 vh = sVx4[k];
        p0 = fmaf(xv[k], vh.x, p0);
        p1 = fmaf(xv[k], vh.y, p1);
        p2 = fmaf(xv[k], vh.z, p2);
        p3 = fmaf(xv[k], vh.w, p3);
      }
      float4 ev = { __expf(p0), __expf(p1), __expf(p2), __expf(p3) };
      *(float4*)(out + (size_t)(lo + i) * 4) = ev;
      s0 += ev.x; s1 += ev.y; s2 += ev.z; s3 += ev.w;
    }
    for (int o = 1; o < 64; o <<= 1) {
      s0 += __shfl_xor(s0, o); s1 += __shfl_xor(s1, o);
      s2 += __shfl_xor(s2, o); s3 += __shfl_xor(s3, o);
    }
    if (lane == 0) red4[wv] = make_float4(s0, s1, s2, s3);
    __syncthreads();
    float4 ra = red4[0], rb = red4[1], rc = red4[2], rd = red4[3];
    float i0 = __builtin_amdgcn_rcpf(ra.x + rb.x + rc.x + rd.x);
    float i1 = __builtin_amdgcn_rcpf(ra.y + rb.y + rc.y + rd.y);
    float i2 = __builtin_amdgcn_rcpf(ra.z + rb.z + rc.z + rd.z);
    float i3 = __builtin_amdgcn_rcpf(ra.w + rb.w + rc.w + rd.w);
    for (int i = t; i < len; i += 256) {
      float4 ev = *(const float4*)(out + (size_t)(lo + i) * 4);
      ev.x *= i0; ev.y *= i1; ev.z *= i2; ev.w *= i3;
      *(float4*)(out + (size_t)(lo + i) * 4) = ev;
    }
  }
}

// ---------------------------------------------------------------------------
extern "C" void kernel_launch(void* const* d_in, const int* in_sizes, int n_in,
                              void* d_out, int out_size, void* d_ws, size_t ws_size,
                              hipStream_t stream) {
  const float* x   = (const float*)d_in[0];
  const int*   seg = (const int*)  d_in[1];
  // d_in[2..10] (lengths, W0,b0,W1,b1,Wlat,blat,Wrho,brho) cancel in the
  // per-segment softmax (shift-invariance) — mathematically unused.
  const float* Wk  = (const float*)d_in[11];
  const float* Wq  = (const float*)d_in[12];
  float* out = (float*)d_out;

  hipLaunchKernelGGL(attn_kernel, dim3(NSEG), dim3(256), 0, stream,
                     x, seg, Wk, Wq, out);
}